// Round 1
// baseline (358.944 us; speedup 1.0000x reference)
//
#include <hip/hip_runtime.h>
#include <hip/hip_bf16.h>

using floatx4 = __attribute__((ext_vector_type(4))) float;
using bf16x8  = __attribute__((ext_vector_type(8))) __bf16;
using uintx4  = __attribute__((ext_vector_type(4))) unsigned int;

#define DEV __device__ __forceinline__

DEV unsigned short f2bf(float f){
  unsigned u = __float_as_uint(f);
  u = (u + 0x7FFFu + ((u >> 16) & 1u)) >> 16;   // RNE, no NaN expected
  return (unsigned short)u;
}
DEV float bf2f(unsigned short h){ return __uint_as_float(((unsigned)h) << 16); }

DEV void gload_lds16(const void* g, void* l){
  __builtin_amdgcn_global_load_lds((const __attribute__((address_space(1))) void*)g,
                                   (__attribute__((address_space(3))) void*)l, 16, 0, 0);
}

DEV void atomicMaxF(float* a, float v){
  if (v >= 0.f) atomicMax((int*)a, __float_as_int(v));
  else          atomicMin((unsigned int*)a, __float_as_uint(v));
}

__global__ __launch_bounds__(256) void k_init(float* stab, float* ksum){
  int t = threadIdx.x;
  if (t < 64) stab[t] = -1e30f;
  for (int i = t; i < 64*64; i += 256) ksum[i] = 0.f;
}

__global__ __launch_bounds__(256) void k_cast(const float* __restrict__ s,
                                              unsigned short* __restrict__ d, int n4){
  int i = blockIdx.x*256 + threadIdx.x;
  int stride = gridDim.x*256;
  for (; i < n4; i += stride){
    float4 v = ((const float4*)s)[i];
    ushort4 o;
    o.x = f2bf(v.x); o.y = f2bf(v.y); o.z = f2bf(v.z); o.w = f2bf(v.w);
    ((ushort4*)d)[i] = o;
  }
}

// C[m,i] = sum_k A[m,k]*W[i,k] + bias[i].  A:[M][K] bf16, W:[Nout][K] bf16.
// m97-style: 128x128 tile, BK=32, 4 waves (2x2), global_load_lds width 16.
template<bool F32OUT>
__global__ __launch_bounds__(256) void k_gemm_bt(const unsigned short* __restrict__ A,
                                                 const unsigned short* __restrict__ W,
                                                 const float* __restrict__ bias,
                                                 void* __restrict__ C,
                                                 int M, int Nout, int K)
{
  __shared__ __align__(16) unsigned short As[128*32];
  __shared__ __align__(16) unsigned short Bs[128*32];
  const int tid = threadIdx.x;
  const int wave = tid >> 6, lane = tid & 63;
  const int m0 = blockIdx.x * 128, n0 = blockIdx.y * 128;
  const int wr = (wave >> 1) * 64, wc = (wave & 1) * 64;
  const int fr = lane & 15, kch = lane >> 4;
  const int sr = lane >> 2;          // staging: row within 16-row segment
  const int sc = (lane & 3) * 8;     // staging: col (8 bf16 = 16B)
  floatx4 acc[4][4] = {};

  for (int kk = 0; kk < K; kk += 32){
    #pragma unroll
    for (int q = 0; q < 2; ++q){
      int seg = wave*2 + q;
      gload_lds16(A + (size_t)(m0 + seg*16 + sr)*K + kk + sc, (char*)As + seg*1024);
      gload_lds16(W + (size_t)(n0 + seg*16 + sr)*K + kk + sc, (char*)Bs + seg*1024);
    }
    __syncthreads();
    bf16x8 af[4], bfr[4];
    #pragma unroll
    for (int m = 0; m < 4; ++m)
      af[m] = *(const bf16x8*)((const char*)As + (wr + m*16 + fr)*64 + kch*16);
    #pragma unroll
    for (int n = 0; n < 4; ++n)
      bfr[n] = *(const bf16x8*)((const char*)Bs + (wc + n*16 + fr)*64 + kch*16);
    #pragma unroll
    for (int m = 0; m < 4; ++m)
      #pragma unroll
      for (int n = 0; n < 4; ++n)
        acc[m][n] = __builtin_amdgcn_mfma_f32_16x16x32_bf16(af[m], bfr[n], acc[m][n], 0, 0, 0);
    __syncthreads();
  }
  #pragma unroll
  for (int m = 0; m < 4; ++m)
  #pragma unroll
  for (int n = 0; n < 4; ++n){
    int col = n0 + wc + n*16 + fr;
    float bv = bias[col];
    #pragma unroll
    for (int r = 0; r < 4; ++r){
      int row = m0 + wr + m*16 + kch*4 + r;
      float v = acc[m][n][r] + bv;
      if (F32OUT) ((float*)C)[(size_t)row*Nout + col] = v;
      else ((unsigned short*)C)[(size_t)row*Nout + col] = f2bf(v);
    }
  }
}

// ---- FAVOR+ -----------------------------------------------------------------
// block: 128 n-rows of one (b,h); J=64, dh=64 fully staged (no K loop).
#define CS 0.35355339059327373f   /* 64^-0.25 */

__global__ __launch_bounds__(256) void k_favor_q(const unsigned short* __restrict__ Qb, // [B*N][D]
                                                 const unsigned short* __restrict__ Pb, // [H][64][64]
                                                 unsigned short* __restrict__ Qp,       // [BH][N][64]
                                                 int Nn, int D, int H)
{
  __shared__ __align__(16) unsigned short Qs[128*64];
  __shared__ __align__(16) unsigned short Ps[64*64];
  __shared__ float diag_s[128];
  const int tid = threadIdx.x, wave = tid >> 6, lane = tid & 63;
  const int bh = blockIdx.y, h = bh % H, b = bh / H;
  const int n0 = blockIdx.x * 128;
  const int fr = lane & 15, kch = lane >> 4;
  const int sr = lane >> 3, sc = (lane & 7) * 8;
  #pragma unroll
  for (int q = 0; q < 4; ++q){
    int seg = wave*4 + q;
    gload_lds16(Qb + ((size_t)b*Nn + n0 + seg*8 + sr)*D + h*64 + sc, (char*)Qs + seg*1024);
  }
  #pragma unroll
  for (int q = 0; q < 2; ++q){
    int seg = wave*2 + q;
    gload_lds16(Pb + (size_t)h*4096 + seg*512 + lane*8, (char*)Ps + seg*1024);
  }
  __syncthreads();
  { // diag = 0.0625*|q|^2, 2 threads/row, staggered to dodge bank conflicts
    int row = tid >> 1, half = tid & 1;
    float s = 0.f;
    for (int i = 0; i < 32; ++i){
      int d = half*32 + ((row + i) & 31);
      float x = bf2f(Qs[row*64 + d]);
      s += x*x;
    }
    float o = __shfl_xor(s, 1);
    if (half == 0) diag_s[row] = 0.0625f * (s + o);
  }
  floatx4 acc[2][4] = {};
  #pragma unroll
  for (int ks = 0; ks < 2; ++ks){
    bf16x8 af[2], bfr[4];
    #pragma unroll
    for (int m = 0; m < 2; ++m)
      af[m] = *(const bf16x8*)((const char*)Qs + (wave*32 + m*16 + fr)*128 + ks*64 + kch*16);
    #pragma unroll
    for (int n = 0; n < 4; ++n)
      bfr[n] = *(const bf16x8*)((const char*)Ps + (n*16 + fr)*128 + ks*64 + kch*16);
    #pragma unroll
    for (int m = 0; m < 2; ++m)
      #pragma unroll
      for (int n = 0; n < 4; ++n)
        acc[m][n] = __builtin_amdgcn_mfma_f32_16x16x32_bf16(af[m], bfr[n], acc[m][n], 0, 0, 0);
  }
  __syncthreads();  // diag_s ready
  #pragma unroll
  for (int m = 0; m < 2; ++m)
  #pragma unroll
  for (int r = 0; r < 4; ++r){
    float mx = -1e30f;
    #pragma unroll
    for (int n = 0; n < 4; ++n) mx = fmaxf(mx, acc[m][n][r]);
    mx = fmaxf(mx, __shfl_xor(mx, 1));
    mx = fmaxf(mx, __shfl_xor(mx, 2));
    mx = fmaxf(mx, __shfl_xor(mx, 4));
    mx = fmaxf(mx, __shfl_xor(mx, 8));
    int row = wave*32 + m*16 + kch*4 + r;
    float dg = diag_s[row];
    float stabv = CS * mx;
    size_t base = ((size_t)bh*Nn + n0 + row)*64;
    #pragma unroll
    for (int n = 0; n < 4; ++n){
      float e = 0.125f * __expf(CS*acc[m][n][r] - dg - stabv) + 1e-4f;
      Qp[base + n*16 + fr] = f2bf(e);
    }
  }
}

__global__ __launch_bounds__(256) void k_favor_k1(const unsigned short* __restrict__ Kb,
                                                  const unsigned short* __restrict__ Pb,
                                                  float* __restrict__ ddout,   // [BH][N][64]
                                                  float* __restrict__ kdiag,   // [BH][N]
                                                  float* __restrict__ stab,    // [BH]
                                                  int Nn, int D, int H)
{
  __shared__ __align__(16) unsigned short Qs[128*64];
  __shared__ __align__(16) unsigned short Ps[64*64];
  __shared__ float wm[4];
  const int tid = threadIdx.x, wave = tid >> 6, lane = tid & 63;
  const int bh = blockIdx.y, h = bh % H, b = bh / H;
  const int n0 = blockIdx.x * 128;
  const int fr = lane & 15, kch = lane >> 4;
  const int sr = lane >> 3, sc = (lane & 7) * 8;
  #pragma unroll
  for (int q = 0; q < 4; ++q){
    int seg = wave*4 + q;
    gload_lds16(Kb + ((size_t)b*Nn + n0 + seg*8 + sr)*D + h*64 + sc, (char*)Qs + seg*1024);
  }
  #pragma unroll
  for (int q = 0; q < 2; ++q){
    int seg = wave*2 + q;
    gload_lds16(Pb + (size_t)h*4096 + seg*512 + lane*8, (char*)Ps + seg*1024);
  }
  __syncthreads();
  {
    int row = tid >> 1, half = tid & 1;
    float s = 0.f;
    for (int i = 0; i < 32; ++i){
      int d = half*32 + ((row + i) & 31);
      float x = bf2f(Qs[row*64 + d]);
      s += x*x;
    }
    float o = __shfl_xor(s, 1);
    if (half == 0) kdiag[(size_t)bh*Nn + n0 + row] = 0.0625f * (s + o);
  }
  floatx4 acc[2][4] = {};
  #pragma unroll
  for (int ks = 0; ks < 2; ++ks){
    bf16x8 af[2], bfr[4];
    #pragma unroll
    for (int m = 0; m < 2; ++m)
      af[m] = *(const bf16x8*)((const char*)Qs + (wave*32 + m*16 + fr)*128 + ks*64 + kch*16);
    #pragma unroll
    for (int n = 0; n < 4; ++n)
      bfr[n] = *(const bf16x8*)((const char*)Ps + (n*16 + fr)*128 + ks*64 + kch*16);
    #pragma unroll
    for (int m = 0; m < 2; ++m)
      #pragma unroll
      for (int n = 0; n < 4; ++n)
        acc[m][n] = __builtin_amdgcn_mfma_f32_16x16x32_bf16(af[m], bfr[n], acc[m][n], 0, 0, 0);
  }
  float mx = -1e30f;
  #pragma unroll
  for (int m = 0; m < 2; ++m)
  #pragma unroll
  for (int r = 0; r < 4; ++r){
    int row = wave*32 + m*16 + kch*4 + r;
    size_t base = ((size_t)bh*Nn + n0 + row)*64;
    #pragma unroll
    for (int n = 0; n < 4; ++n){
      float v = CS * acc[m][n][r];
      mx = fmaxf(mx, v);
      ddout[base + n*16 + fr] = v;
    }
  }
  #pragma unroll
  for (int off = 1; off < 64; off <<= 1) mx = fmaxf(mx, __shfl_xor(mx, off));
  if (lane == 0) wm[wave] = mx;
  __syncthreads();
  if (tid == 0) atomicMaxF(&stab[bh], fmaxf(fmaxf(wm[0],wm[1]), fmaxf(wm[2],wm[3])));
}

// exp + transpose to [BH][J=64][N] + ksum
__global__ __launch_bounds__(256) void k_favor_k2(const float* __restrict__ dd,
                                                  const float* __restrict__ kdiag,
                                                  const float* __restrict__ stab,
                                                  unsigned short* __restrict__ Ktp,  // [BH][64][N]
                                                  float* __restrict__ ksum,          // [BH][64]
                                                  int Nn)
{
  __shared__ __align__(16) unsigned short T[64*136];
  const int tid = threadIdx.x;
  const int bh = blockIdx.y, n0 = blockIdx.x * 128;
  const float stv = stab[bh];
  for (int it = 0; it < 32; ++it){
    int idx = it*256 + tid;       // 8192 = 128n x 64j
    int n = idx >> 6, j = idx & 63;
    float v = dd[((size_t)bh*Nn + n0 + n)*64 + j];
    float kp = 0.125f*__expf(v - kdiag[(size_t)bh*Nn + n0 + n] - stv) + 1e-4f;
    T[j*136 + n] = f2bf(kp);
  }
  __syncthreads();
  {
    int j = tid >> 2, part = tid & 3;
    float s = 0.f;
    for (int i = 0; i < 32; ++i) s += bf2f(T[j*136 + part*32 + i]);
    s += __shfl_xor(s, 1); s += __shfl_xor(s, 2);
    if (part == 0) atomicAdd(&ksum[bh*64 + j], s);
  }
  for (int it = 0; it < 4; ++it){
    int sidx = it*256 + tid;      // 1024 vec8 slots
    int j = sidx >> 4, nn = (sidx & 15) * 8;
    uintx4 v = *(const uintx4*)((const char*)T + (j*136 + nn)*2);
    *(uintx4*)(Ktp + ((size_t)bh*64 + j)*Nn + n0 + nn) = v;
  }
}

__global__ __launch_bounds__(256) void k_vtrans(const unsigned short* __restrict__ Vb,  // [B*N][D]
                                                unsigned short* __restrict__ Vtp,       // [BH][64][N]
                                                int Nn, int D, int H)
{
  __shared__ __align__(16) unsigned short T[64*136];
  const int tid = threadIdx.x;
  const int bh = blockIdx.y, h = bh % H, b = bh / H;
  const int n0 = blockIdx.x * 128;
  for (int it = 0; it < 4; ++it){
    int s8 = it*256 + tid;        // 1024 vec8 slots over [128n][64d]
    int n = s8 >> 3, d0 = (s8 & 7) * 8;
    uintx4 v = *(const uintx4*)(Vb + ((size_t)b*Nn + n0 + n)*D + h*64 + d0);
    const unsigned short* us = (const unsigned short*)&v;
    #pragma unroll
    for (int ii = 0; ii < 8; ++ii) T[(d0+ii)*136 + n] = us[ii];
  }
  __syncthreads();
  for (int it = 0; it < 4; ++it){
    int sidx = it*256 + tid;
    int d = sidx >> 4, nn = (sidx & 15) * 8;
    uintx4 v = *(const uintx4*)((const char*)T + (d*136 + nn)*2);
    *(uintx4*)(Vtp + ((size_t)bh*64 + d)*Nn + n0 + nn) = v;
  }
}

// kv partial: [KS][BH][j=64][d=64] f32, K split 8 ways over N=4096
__global__ __launch_bounds__(256) void k_kv(const unsigned short* __restrict__ Ktp,
                                            const unsigned short* __restrict__ Vtp,
                                            float* __restrict__ kvp, int Nn)
{
  __shared__ __align__(16) unsigned short As[64*32];
  __shared__ __align__(16) unsigned short Bs[64*32];
  const int tid = threadIdx.x, wave = tid >> 6, lane = tid & 63;
  const int ks = blockIdx.x, bh = blockIdx.y;
  const int base = ks * 512;
  const int fr = lane & 15, kch = lane >> 4;
  const int sr = lane >> 2, sc = (lane & 3) * 8;
  floatx4 acc[4] = {};
  for (int kk = 0; kk < 512; kk += 32){
    gload_lds16(Ktp + ((size_t)bh*64 + wave*16 + sr)*Nn + base + kk + sc, (char*)As + wave*1024);
    gload_lds16(Vtp + ((size_t)bh*64 + wave*16 + sr)*Nn + base + kk + sc, (char*)Bs + wave*1024);
    __syncthreads();
    bf16x8 af = *(const bf16x8*)((const char*)As + (wave*16 + fr)*64 + kch*16);
    #pragma unroll
    for (int n = 0; n < 4; ++n){
      bf16x8 bfr = *(const bf16x8*)((const char*)Bs + (n*16 + fr)*64 + kch*16);
      acc[n] = __builtin_amdgcn_mfma_f32_16x16x32_bf16(af, bfr, acc[n], 0, 0, 0);
    }
    __syncthreads();
  }
  #pragma unroll
  for (int n = 0; n < 4; ++n)
  #pragma unroll
  for (int r = 0; r < 4; ++r){
    int j = wave*16 + kch*4 + r;
    int d = n*16 + fr;
    kvp[((size_t)(ks*64 + bh)*64 + j)*64 + d] = acc[n][r];
  }
}

// reduce over KS and transpose -> Kvt[BH][d=64][j=64] bf16
__global__ __launch_bounds__(256) void k_kvred(const float* __restrict__ kvp,
                                               unsigned short* __restrict__ Kvt){
  const int bh = blockIdx.x, tid = threadIdx.x;
  for (int i = 0; i < 16; ++i){
    int idx = i*256 + tid;
    int j = idx >> 6, d = idx & 63;
    float s = 0.f;
    #pragma unroll
    for (int ks = 0; ks < 8; ++ks) s += kvp[((size_t)(ks*64 + bh)*64 + j)*64 + d];
    Kvt[((size_t)bh*64 + d)*64 + j] = f2bf(s);
  }
}

__global__ __launch_bounds__(256) void k_qkv(const unsigned short* __restrict__ Qp,   // [BH][N][64]
                                             const unsigned short* __restrict__ Kvt,  // [BH][64][64]
                                             const float* __restrict__ ksum,          // [BH][64]
                                             unsigned short* __restrict__ att,        // [B*N][D]
                                             int Nn, int D, int H)
{
  __shared__ __align__(16) unsigned short Qs[128*64];
  __shared__ __align__(16) unsigned short Ks[64*64];
  __shared__ float ksum_s[64];
  __shared__ float nrm[128];
  const int tid = threadIdx.x, wave = tid >> 6, lane = tid & 63;
  const int bh = blockIdx.y, h = bh % H, b = bh / H;
  const int n0 = blockIdx.x * 128;
  const int fr = lane & 15, kch = lane >> 4;
  const int sr = lane >> 3, sc = (lane & 7) * 8;
  #pragma unroll
  for (int q = 0; q < 4; ++q){
    int seg = wave*4 + q;
    gload_lds16(Qp + ((size_t)bh*Nn + n0 + seg*8 + sr)*64 + sc, (char*)Qs + seg*1024);
  }
  #pragma unroll
  for (int q = 0; q < 2; ++q){
    int seg = wave*2 + q;
    gload_lds16(Kvt + (size_t)bh*4096 + seg*512 + lane*8, (char*)Ks + seg*1024);
  }
  if (tid < 64) ksum_s[tid] = ksum[bh*64 + tid];
  __syncthreads();
  if (tid < 128){
    float s = 0.f;
    for (int i = 0; i < 64; ++i){
      int j = (tid + i) & 63;
      s += bf2f(Qs[tid*64 + j]) * ksum_s[j];
    }
    nrm[tid] = fmaxf(s, 0.01f);
  }
  floatx4 acc[2][4] = {};
  #pragma unroll
  for (int ks2 = 0; ks2 < 2; ++ks2){
    bf16x8 af[2], bfr[4];
    #pragma unroll
    for (int m = 0; m < 2; ++m)
      af[m] = *(const bf16x8*)((const char*)Qs + (wave*32 + m*16 + fr)*128 + ks2*64 + kch*16);
    #pragma unroll
    for (int n = 0; n < 4; ++n)
      bfr[n] = *(const bf16x8*)((const char*)Ks + (n*16 + fr)*128 + ks2*64 + kch*16);
    #pragma unroll
    for (int m = 0; m < 2; ++m)
      #pragma unroll
      for (int n = 0; n < 4; ++n)
        acc[m][n] = __builtin_amdgcn_mfma_f32_16x16x32_bf16(af[m], bfr[n], acc[m][n], 0, 0, 0);
  }
  __syncthreads();  // nrm ready
  #pragma unroll
  for (int m = 0; m < 2; ++m)
  #pragma unroll
  for (int r = 0; r < 4; ++r){
    int row = wave*32 + m*16 + kch*4 + r;
    float inv = 1.0f / nrm[row];
    #pragma unroll
    for (int n = 0; n < 4; ++n){
      float v = acc[m][n][r] * inv;
      att[((size_t)b*Nn + n0 + row)*D + h*64 + n*16 + fr] = f2bf(v);
    }
  }
}

extern "C" void kernel_launch(void* const* d_in, const int* in_sizes, int n_in,
                              void* d_out, int out_size, void* d_ws, size_t ws_size,
                              hipStream_t stream)
{
  (void)in_sizes; (void)n_in; (void)out_size; (void)ws_size;
  const float* query = (const float*)d_in[0];
  const float* Wq = (const float*)d_in[1];
  const float* bq = (const float*)d_in[2];
  const float* Wk = (const float*)d_in[3];
  const float* bk = (const float*)d_in[4];
  const float* Wv = (const float*)d_in[5];
  const float* bv = (const float*)d_in[6];
  const float* Wo = (const float*)d_in[7];
  const float* bo = (const float*)d_in[8];
  const float* proj = (const float*)d_in[9];

  const int B = 4, N = 4096, D = 1024, H = 16;
  const size_t NT = (size_t)B*N*D;       // 16,777,216

  char* ws = (char*)d_ws;
  unsigned short* qbf = (unsigned short*)ws;               // NT bf16 (reused as att)
  unsigned short* wqb = (unsigned short*)(ws + 33554432);
  unsigned short* wkb = wqb + 1048576;
  unsigned short* wvb = wkb + 1048576;
  unsigned short* wob = wvb + 1048576;
  unsigned short* pjb = wob + 1048576;                     // 65536 bf16
  unsigned short* qb  = pjb + 65536;                       // NT bf16
  unsigned short* kb  = qb + NT;                           // NT bf16 (reused as Vtp)
  unsigned short* vb  = kb + NT;                           // NT bf16
  float* kdiag = (float*)(vb + NT);                        // B*H*N f32
  float* stab  = kdiag + 262144;                           // 64 f32
  float* ksum  = stab + 64;                                // 4096 f32
  unsigned short* ktp = (unsigned short*)(ksum + 4096);    // [BH][64][N] bf16
  float* kvp = (float*)(ktp + NT);                         // 8*64*64*64 f32
  unsigned short* kvt = (unsigned short*)(kvp + 2097152);  // [BH][64][64] bf16
  // d_out (67MB f32) doubles as scratch:
  float* dd = (float*)d_out;                               // [BH][N][64] f32
  unsigned short* qprime = (unsigned short*)d_out;         // [BH][N][64] bf16 (after dd is dead)
  unsigned short* att = qbf;                               // [B*N][D] bf16 (qbf dead after GEMMs)
  unsigned short* vtp = kb;                                // [BH][64][N] bf16 (kb dead after k1)

  k_init<<<1, 256, 0, stream>>>(stab, ksum);
  k_cast<<<2048, 256, 0, stream>>>(query, qbf, (int)(NT/4));
  k_cast<<<1024, 256, 0, stream>>>(Wq, wqb, 262144);
  k_cast<<<1024, 256, 0, stream>>>(Wk, wkb, 262144);
  k_cast<<<1024, 256, 0, stream>>>(Wv, wvb, 262144);
  k_cast<<<1024, 256, 0, stream>>>(Wo, wob, 262144);
  k_cast<<<64, 256, 0, stream>>>(proj, pjb, 16384);

  dim3 gg(128, 8);
  k_gemm_bt<false><<<gg, 256, 0, stream>>>(qbf, wqb, bq, qb, B*N, D, D);
  k_gemm_bt<false><<<gg, 256, 0, stream>>>(qbf, wkb, bk, kb, B*N, D, D);
  k_gemm_bt<false><<<gg, 256, 0, stream>>>(qbf, wvb, bv, vb, B*N, D, D);

  dim3 gf(32, 64);
  k_favor_k1<<<gf, 256, 0, stream>>>(kb, pjb, dd, kdiag, stab, N, D, H);
  k_favor_k2<<<gf, 256, 0, stream>>>(dd, kdiag, stab, ktp, ksum, N);
  k_favor_q <<<gf, 256, 0, stream>>>(qb, pjb, qprime, N, D, H);
  k_vtrans  <<<gf, 256, 0, stream>>>(vb, vtp, N, D, H);

  k_kv<<<dim3(8, 64), 256, 0, stream>>>(ktp, vtp, kvp, N);
  k_kvred<<<64, 256, 0, stream>>>(kvp, kvt);
  k_qkv<<<gf, 256, 0, stream>>>(qprime, kvt, ksum, att, N, D, H);

  k_gemm_bt<true><<<gg, 256, 0, stream>>>(att, wob, bo, d_out, B*N, D, D);
}

// Round 2
// 308.221 us; speedup vs baseline: 1.1646x; 1.1646x over previous
//
#include <hip/hip_runtime.h>
#include <hip/hip_bf16.h>

using floatx4 = __attribute__((ext_vector_type(4))) float;
using bf16x8  = __attribute__((ext_vector_type(8))) __bf16;
using uintx4  = __attribute__((ext_vector_type(4))) unsigned int;

#define DEV __device__ __forceinline__

DEV unsigned short f2bf(float f){
  unsigned u = __float_as_uint(f);
  u = (u + 0x7FFFu + ((u >> 16) & 1u)) >> 16;   // RNE, no NaN expected
  return (unsigned short)u;
}
DEV float bf2f(unsigned short h){ return __uint_as_float(((unsigned)h) << 16); }

DEV void gload_lds16(const void* g, void* l){
  __builtin_amdgcn_global_load_lds((const __attribute__((address_space(1))) void*)g,
                                   (__attribute__((address_space(3))) void*)l, 16, 0, 0);
}

DEV void atomicMaxF(float* a, float v){
  if (v >= 0.f) atomicMax((int*)a, __float_as_int(v));
  else          atomicMin((unsigned int*)a, __float_as_uint(v));
}

#define SBAR do{ __builtin_amdgcn_sched_barrier(0); __builtin_amdgcn_s_barrier(); \
                 __builtin_amdgcn_sched_barrier(0); }while(0)

__global__ __launch_bounds__(256) void k_init(float* stab, float* ksum){
  int t = threadIdx.x;
  if (t < 64) stab[t] = -1e30f;
  for (int i = t; i < 64*64; i += 256) ksum[i] = 0.f;
}

__global__ __launch_bounds__(256) void k_cast(const float* __restrict__ s,
                                              unsigned short* __restrict__ d, int n4){
  int i = blockIdx.x*256 + threadIdx.x;
  int stride = gridDim.x*256;
  for (; i < n4; i += stride){
    float4 v = ((const float4*)s)[i];
    ushort4 o;
    o.x = f2bf(v.x); o.y = f2bf(v.y); o.z = f2bf(v.z); o.w = f2bf(v.w);
    ((ushort4*)d)[i] = o;
  }
}

// ---------------------------------------------------------------------------
// 256x256-tile GEMM, deep-pipelined (4-deep LDS circular buffer, counted vmcnt).
// C[m,n] = sum_k A[m,k]*W[n,k] + bias[n].  A:[M][K] bf16, W:[Nout][K] bf16.
// 8 waves (2Mx4N), BK=32, LDS = 4 bufs x (A 16KB + B 16KB) = 128 KB.
// OUTMODE 0: bf16 out, cols split into 3 chunks of 1024 (fused QKV).
// OUTMODE 1: f32 out, single output.
template<int OUTMODE>
__global__ __launch_bounds__(512, 2) void gemm256(
    const unsigned short* __restrict__ A,
    const unsigned short* __restrict__ W,
    const float* __restrict__ bias0, const float* __restrict__ bias1,
    const float* __restrict__ bias2,
    unsigned short* __restrict__ out0, unsigned short* __restrict__ out1,
    unsigned short* __restrict__ out2,
    float* __restrict__ outf, int M, int Nout, int K)
{
  __shared__ __align__(16) char lds[131072];
  const int tid  = threadIdx.x;
  const int wid  = tid >> 6, lane = tid & 63;
  const int wr   = wid >> 2, wc = wid & 3;        // 2 x 4 wave grid
  const int fr   = lane & 15, kch = lane >> 4;
  const int m0   = blockIdx.x * 256, n0 = blockIdx.y * 256;
  const int NTt  = K >> 5;                        // K-tiles of 32
  const size_t Kb = (size_t)K * 2;                // bytes per row

  const int st_r = lane >> 2;                     // staging: row in 16-row seg
  const int st_c = (lane & 3) * 16;               // staging: byte in row

  // wave stages rows [wid*32, wid*32+32) of A and of W per tile (2+2 gloads)
  auto stageA = [&](int t){
    char* dst = lds + (size_t)(t & 3) * 32768 + wid*32*64;
    const char* src = (const char*)A + ((size_t)(m0 + wid*32 + st_r))*Kb + t*64 + st_c;
    gload_lds16(src, dst);
    gload_lds16(src + 16*Kb, dst + 1024);
  };
  auto stageB = [&](int t){
    char* dst = lds + (size_t)(t & 3) * 32768 + 16384 + wid*32*64;
    const char* src = (const char*)W + ((size_t)(n0 + wid*32 + st_r))*Kb + t*64 + st_c;
    gload_lds16(src, dst);
    gload_lds16(src + 16*Kb, dst + 1024);
  };

  // prologue: stage tiles 0,1,2 (12 loads in flight per wave)
  #pragma unroll
  for (int t = 0; t < 3; ++t){
    if (t < NTt){ stageA(t); stageB(t); }
  }

  const int aoff = (wr*128 + fr)*64 + kch*16;
  const int boff = 16384 + (wc*64 + fr)*64 + kch*16;
  floatx4 acc[8][4] = {};
  bf16x8 a0[4], a1[4], bfr[4];

  for (int T = 0; T < NTt; ++T){
    if (T + 2 < NTt)      asm volatile("s_waitcnt vmcnt(8)" ::: "memory");
    else if (T + 1 < NTt) asm volatile("s_waitcnt vmcnt(4)" ::: "memory");
    else                  asm volatile("s_waitcnt vmcnt(0)" ::: "memory");
    SBAR;                                          // tile T resident for all waves
    const char* buf = lds + (size_t)(T & 3) * 32768;
    // ---- phase 1: read A(mf0-3) + B(all), stage A of T+3, MFMA quadrant 1
    #pragma unroll
    for (int mf = 0; mf < 4; ++mf) a0[mf]  = *(const bf16x8*)(buf + aoff + mf*1024);
    #pragma unroll
    for (int nf = 0; nf < 4; ++nf) bfr[nf] = *(const bf16x8*)(buf + boff + nf*1024);
    if (T + 3 < NTt) stageA(T + 3);
    SBAR;
    __builtin_amdgcn_s_setprio(1);
    #pragma unroll
    for (int mf = 0; mf < 4; ++mf)
      #pragma unroll
      for (int nf = 0; nf < 4; ++nf)
        acc[mf][nf] = __builtin_amdgcn_mfma_f32_16x16x32_bf16(a0[mf], bfr[nf], acc[mf][nf], 0, 0, 0);
    __builtin_amdgcn_s_setprio(0);
    SBAR;
    // ---- phase 2: read A(mf4-7), stage B of T+3, MFMA quadrant 2
    #pragma unroll
    for (int mf = 0; mf < 4; ++mf) a1[mf] = *(const bf16x8*)(buf + aoff + (4+mf)*1024);
    if (T + 3 < NTt) stageB(T + 3);
    SBAR;
    __builtin_amdgcn_s_setprio(1);
    #pragma unroll
    for (int mf = 0; mf < 4; ++mf)
      #pragma unroll
      for (int nf = 0; nf < 4; ++nf)
        acc[4+mf][nf] = __builtin_amdgcn_mfma_f32_16x16x32_bf16(a1[mf], bfr[nf], acc[4+mf][nf], 0, 0, 0);
    __builtin_amdgcn_s_setprio(0);
  }

  // epilogue
  if (OUTMODE == 0){
    const int which = n0 >> 10;
    const float* bb = (which == 0) ? bias0 : (which == 1) ? bias1 : bias2;
    unsigned short* oo = (which == 0) ? out0 : (which == 1) ? out1 : out2;
    #pragma unroll
    for (int nf = 0; nf < 4; ++nf){
      int col = n0 + wc*64 + nf*16 + fr;
      int cl  = col & 1023;
      float bv = bb[cl];
      #pragma unroll
      for (int mf = 0; mf < 8; ++mf)
        #pragma unroll
        for (int r = 0; r < 4; ++r){
          int row = m0 + wr*128 + mf*16 + kch*4 + r;
          oo[(size_t)row*1024 + cl] = f2bf(acc[mf][nf][r] + bv);
        }
    }
  } else {
    #pragma unroll
    for (int nf = 0; nf < 4; ++nf){
      int col = n0 + wc*64 + nf*16 + fr;
      float bv = bias0[col];
      #pragma unroll
      for (int mf = 0; mf < 8; ++mf)
        #pragma unroll
        for (int r = 0; r < 4; ++r){
          int row = m0 + wr*128 + mf*16 + kch*4 + r;
          outf[(size_t)row*Nout + col] = acc[mf][nf][r] + bv;
        }
    }
  }
}

// ---- FAVOR+ -----------------------------------------------------------------
#define CS 0.35355339059327373f   /* 64^-0.25 */

__global__ __launch_bounds__(256) void k_favor_q(const unsigned short* __restrict__ Qb, // [B*N][D]
                                                 const unsigned short* __restrict__ Pb, // [H][64][64]
                                                 unsigned short* __restrict__ Qp,       // [BH][N][64]
                                                 int Nn, int D, int H)
{
  __shared__ __align__(16) unsigned short Qs[128*64];
  __shared__ __align__(16) unsigned short Ps[64*64];
  __shared__ float diag_s[128];
  const int tid = threadIdx.x, wave = tid >> 6, lane = tid & 63;
  const int bh = blockIdx.y, h = bh % H, b = bh / H;
  const int n0 = blockIdx.x * 128;
  const int fr = lane & 15, kch = lane >> 4;
  const int sr = lane >> 3, sc = (lane & 7) * 8;
  #pragma unroll
  for (int q = 0; q < 4; ++q){
    int seg = wave*4 + q;
    gload_lds16(Qb + ((size_t)b*Nn + n0 + seg*8 + sr)*D + h*64 + sc, (char*)Qs + seg*1024);
  }
  #pragma unroll
  for (int q = 0; q < 2; ++q){
    int seg = wave*2 + q;
    gload_lds16(Pb + (size_t)h*4096 + seg*512 + lane*8, (char*)Ps + seg*1024);
  }
  __syncthreads();
  {
    int row = tid >> 1, half = tid & 1;
    float s = 0.f;
    for (int i = 0; i < 32; ++i){
      int d = half*32 + ((row + i) & 31);
      float x = bf2f(Qs[row*64 + d]);
      s += x*x;
    }
    float o = __shfl_xor(s, 1);
    if (half == 0) diag_s[row] = 0.0625f * (s + o);
  }
  floatx4 acc[2][4] = {};
  #pragma unroll
  for (int ks = 0; ks < 2; ++ks){
    bf16x8 af[2], bfr[4];
    #pragma unroll
    for (int m = 0; m < 2; ++m)
      af[m] = *(const bf16x8*)((const char*)Qs + (wave*32 + m*16 + fr)*128 + ks*64 + kch*16);
    #pragma unroll
    for (int n = 0; n < 4; ++n)
      bfr[n] = *(const bf16x8*)((const char*)Ps + (n*16 + fr)*128 + ks*64 + kch*16);
    #pragma unroll
    for (int m = 0; m < 2; ++m)
      #pragma unroll
      for (int n = 0; n < 4; ++n)
        acc[m][n] = __builtin_amdgcn_mfma_f32_16x16x32_bf16(af[m], bfr[n], acc[m][n], 0, 0, 0);
  }
  __syncthreads();
  #pragma unroll
  for (int m = 0; m < 2; ++m)
  #pragma unroll
  for (int r = 0; r < 4; ++r){
    float mx = -1e30f;
    #pragma unroll
    for (int n = 0; n < 4; ++n) mx = fmaxf(mx, acc[m][n][r]);
    mx = fmaxf(mx, __shfl_xor(mx, 1));
    mx = fmaxf(mx, __shfl_xor(mx, 2));
    mx = fmaxf(mx, __shfl_xor(mx, 4));
    mx = fmaxf(mx, __shfl_xor(mx, 8));
    int row = wave*32 + m*16 + kch*4 + r;
    float dg = diag_s[row];
    float stabv = CS * mx;
    size_t base = ((size_t)bh*Nn + n0 + row)*64;
    #pragma unroll
    for (int n = 0; n < 4; ++n){
      float e = 0.125f * __expf(CS*acc[m][n][r] - dg - stabv) + 1e-4f;
      Qp[base + n*16 + fr] = f2bf(e);
    }
  }
}

__global__ __launch_bounds__(256) void k_favor_k1(const unsigned short* __restrict__ Kb,
                                                  const unsigned short* __restrict__ Pb,
                                                  float* __restrict__ ddout,   // [BH][N][64]
                                                  float* __restrict__ kdiag,   // [BH][N]
                                                  float* __restrict__ stab,    // [BH]
                                                  int Nn, int D, int H)
{
  __shared__ __align__(16) unsigned short Qs[128*64];
  __shared__ __align__(16) unsigned short Ps[64*64];
  __shared__ float wm[4];
  const int tid = threadIdx.x, wave = tid >> 6, lane = tid & 63;
  const int bh = blockIdx.y, h = bh % H, b = bh / H;
  const int n0 = blockIdx.x * 128;
  const int fr = lane & 15, kch = lane >> 4;
  const int sr = lane >> 3, sc = (lane & 7) * 8;
  #pragma unroll
  for (int q = 0; q < 4; ++q){
    int seg = wave*4 + q;
    gload_lds16(Kb + ((size_t)b*Nn + n0 + seg*8 + sr)*D + h*64 + sc, (char*)Qs + seg*1024);
  }
  #pragma unroll
  for (int q = 0; q < 2; ++q){
    int seg = wave*2 + q;
    gload_lds16(Pb + (size_t)h*4096 + seg*512 + lane*8, (char*)Ps + seg*1024);
  }
  __syncthreads();
  {
    int row = tid >> 1, half = tid & 1;
    float s = 0.f;
    for (int i = 0; i < 32; ++i){
      int d = half*32 + ((row + i) & 31);
      float x = bf2f(Qs[row*64 + d]);
      s += x*x;
    }
    float o = __shfl_xor(s, 1);
    if (half == 0) kdiag[(size_t)bh*Nn + n0 + row] = 0.0625f * (s + o);
  }
  floatx4 acc[2][4] = {};
  #pragma unroll
  for (int ks = 0; ks < 2; ++ks){
    bf16x8 af[2], bfr[4];
    #pragma unroll
    for (int m = 0; m < 2; ++m)
      af[m] = *(const bf16x8*)((const char*)Qs + (wave*32 + m*16 + fr)*128 + ks*64 + kch*16);
    #pragma unroll
    for (int n = 0; n < 4; ++n)
      bfr[n] = *(const bf16x8*)((const char*)Ps + (n*16 + fr)*128 + ks*64 + kch*16);
    #pragma unroll
    for (int m = 0; m < 2; ++m)
      #pragma unroll
      for (int n = 0; n < 4; ++n)
        acc[m][n] = __builtin_amdgcn_mfma_f32_16x16x32_bf16(af[m], bfr[n], acc[m][n], 0, 0, 0);
  }
  float mx = -1e30f;
  #pragma unroll
  for (int m = 0; m < 2; ++m)
  #pragma unroll
  for (int r = 0; r < 4; ++r){
    int row = wave*32 + m*16 + kch*4 + r;
    size_t base = ((size_t)bh*Nn + n0 + row)*64;
    #pragma unroll
    for (int n = 0; n < 4; ++n){
      float v = CS * acc[m][n][r];
      mx = fmaxf(mx, v);
      ddout[base + n*16 + fr] = v;
    }
  }
  #pragma unroll
  for (int off = 1; off < 64; off <<= 1) mx = fmaxf(mx, __shfl_xor(mx, off));
  if (lane == 0) wm[wave] = mx;
  __syncthreads();
  if (tid == 0) atomicMaxF(&stab[bh], fmaxf(fmaxf(wm[0],wm[1]), fmaxf(wm[2],wm[3])));
}

__global__ __launch_bounds__(256) void k_favor_k2(const float* __restrict__ dd,
                                                  const float* __restrict__ kdiag,
                                                  const float* __restrict__ stab,
                                                  unsigned short* __restrict__ Ktp,  // [BH][64][N]
                                                  float* __restrict__ ksum,          // [BH][64]
                                                  int Nn)
{
  __shared__ __align__(16) unsigned short T[64*136];
  const int tid = threadIdx.x;
  const int bh = blockIdx.y, n0 = blockIdx.x * 128;
  const float stv = stab[bh];
  for (int it = 0; it < 32; ++it){
    int idx = it*256 + tid;
    int n = idx >> 6, j = idx & 63;
    float v = dd[((size_t)bh*Nn + n0 + n)*64 + j];
    float kp = 0.125f*__expf(v - kdiag[(size_t)bh*Nn + n0 + n] - stv) + 1e-4f;
    T[j*136 + n] = f2bf(kp);
  }
  __syncthreads();
  {
    int j = tid >> 2, part = tid & 3;
    float s = 0.f;
    for (int i = 0; i < 32; ++i) s += bf2f(T[j*136 + part*32 + i]);
    s += __shfl_xor(s, 1); s += __shfl_xor(s, 2);
    if (part == 0) atomicAdd(&ksum[bh*64 + j], s);
  }
  for (int it = 0; it < 4; ++it){
    int sidx = it*256 + tid;
    int j = sidx >> 4, nn = (sidx & 15) * 8;
    uintx4 v = *(const uintx4*)((const char*)T + (j*136 + nn)*2);
    *(uintx4*)(Ktp + ((size_t)bh*64 + j)*Nn + n0 + nn) = v;
  }
}

__global__ __launch_bounds__(256) void k_vtrans(const unsigned short* __restrict__ Vb,
                                                unsigned short* __restrict__ Vtp,
                                                int Nn, int D, int H)
{
  __shared__ __align__(16) unsigned short T[64*136];
  const int tid = threadIdx.x;
  const int bh = blockIdx.y, h = bh % H, b = bh / H;
  const int n0 = blockIdx.x * 128;
  for (int it = 0; it < 4; ++it){
    int s8 = it*256 + tid;
    int n = s8 >> 3, d0 = (s8 & 7) * 8;
    uintx4 v = *(const uintx4*)(Vb + ((size_t)b*Nn + n0 + n)*D + h*64 + d0);
    const unsigned short* us = (const unsigned short*)&v;
    #pragma unroll
    for (int ii = 0; ii < 8; ++ii) T[(d0+ii)*136 + n] = us[ii];
  }
  __syncthreads();
  for (int it = 0; it < 4; ++it){
    int sidx = it*256 + tid;
    int d = sidx >> 4, nn = (sidx & 15) * 8;
    uintx4 v = *(const uintx4*)((const char*)T + (d*136 + nn)*2);
    *(uintx4*)(Vtp + ((size_t)bh*64 + d)*Nn + n0 + nn) = v;
  }
}

__global__ __launch_bounds__(256) void k_kv(const unsigned short* __restrict__ Ktp,
                                            const unsigned short* __restrict__ Vtp,
                                            float* __restrict__ kvp, int Nn)
{
  __shared__ __align__(16) unsigned short As[64*32];
  __shared__ __align__(16) unsigned short Bs[64*32];
  const int tid = threadIdx.x, wave = tid >> 6, lane = tid & 63;
  const int ks = blockIdx.x, bh = blockIdx.y;
  const int base = ks * 512;
  const int fr = lane & 15, kch = lane >> 4;
  const int sr = lane >> 2, sc = (lane & 3) * 8;
  floatx4 acc[4] = {};
  for (int kk = 0; kk < 512; kk += 32){
    gload_lds16(Ktp + ((size_t)bh*64 + wave*16 + sr)*Nn + base + kk + sc, (char*)As + wave*1024);
    gload_lds16(Vtp + ((size_t)bh*64 + wave*16 + sr)*Nn + base + kk + sc, (char*)Bs + wave*1024);
    __syncthreads();
    bf16x8 af = *(const bf16x8*)((const char*)As + (wave*16 + fr)*64 + kch*16);
    #pragma unroll
    for (int n = 0; n < 4; ++n){
      bf16x8 bfr = *(const bf16x8*)((const char*)Bs + (n*16 + fr)*64 + kch*16);
      acc[n] = __builtin_amdgcn_mfma_f32_16x16x32_bf16(af, bfr, acc[n], 0, 0, 0);
    }
    __syncthreads();
  }
  #pragma unroll
  for (int n = 0; n < 4; ++n)
  #pragma unroll
  for (int r = 0; r < 4; ++r){
    int j = wave*16 + kch*4 + r;
    int d = n*16 + fr;
    kvp[((size_t)(ks*64 + bh)*64 + j)*64 + d] = acc[n][r];
  }
}

__global__ __launch_bounds__(256) void k_kvred(const float* __restrict__ kvp,
                                               unsigned short* __restrict__ Kvt){
  const int bh = blockIdx.x, tid = threadIdx.x;
  for (int i = 0; i < 16; ++i){
    int idx = i*256 + tid;
    int j = idx >> 6, d = idx & 63;
    float s = 0.f;
    #pragma unroll
    for (int ks = 0; ks < 8; ++ks) s += kvp[((size_t)(ks*64 + bh)*64 + j)*64 + d];
    Kvt[((size_t)bh*64 + d)*64 + j] = f2bf(s);
  }
}

__global__ __launch_bounds__(256) void k_qkv(const unsigned short* __restrict__ Qp,
                                             const unsigned short* __restrict__ Kvt,
                                             const float* __restrict__ ksum,
                                             unsigned short* __restrict__ att,
                                             int Nn, int D, int H)
{
  __shared__ __align__(16) unsigned short Qs[128*64];
  __shared__ __align__(16) unsigned short Ks[64*64];
  __shared__ float ksum_s[64];
  __shared__ float nrm[128];
  const int tid = threadIdx.x, wave = tid >> 6, lane = tid & 63;
  const int bh = blockIdx.y, h = bh % H, b = bh / H;
  const int n0 = blockIdx.x * 128;
  const int fr = lane & 15, kch = lane >> 4;
  const int sr = lane >> 3, sc = (lane & 7) * 8;
  #pragma unroll
  for (int q = 0; q < 4; ++q){
    int seg = wave*4 + q;
    gload_lds16(Qp + ((size_t)bh*Nn + n0 + seg*8 + sr)*64 + sc, (char*)Qs + seg*1024);
  }
  #pragma unroll
  for (int q = 0; q < 2; ++q){
    int seg = wave*2 + q;
    gload_lds16(Kvt + (size_t)bh*4096 + seg*512 + lane*8, (char*)Ks + seg*1024);
  }
  if (tid < 64) ksum_s[tid] = ksum[bh*64 + tid];
  __syncthreads();
  if (tid < 128){
    float s = 0.f;
    for (int i = 0; i < 64; ++i){
      int j = (tid + i) & 63;
      s += bf2f(Qs[tid*64 + j]) * ksum_s[j];
    }
    nrm[tid] = fmaxf(s, 0.01f);
  }
  floatx4 acc[2][4] = {};
  #pragma unroll
  for (int ks2 = 0; ks2 < 2; ++ks2){
    bf16x8 af[2], bfr[4];
    #pragma unroll
    for (int m = 0; m < 2; ++m)
      af[m] = *(const bf16x8*)((const char*)Qs + (wave*32 + m*16 + fr)*128 + ks2*64 + kch*16);
    #pragma unroll
    for (int n = 0; n < 4; ++n)
      bfr[n] = *(const bf16x8*)((const char*)Ks + (n*16 + fr)*128 + ks2*64 + kch*16);
    #pragma unroll
    for (int m = 0; m < 2; ++m)
      #pragma unroll
      for (int n = 0; n < 4; ++n)
        acc[m][n] = __builtin_amdgcn_mfma_f32_16x16x32_bf16(af[m], bfr[n], acc[m][n], 0, 0, 0);
  }
  __syncthreads();
  #pragma unroll
  for (int m = 0; m < 2; ++m)
  #pragma unroll
  for (int r = 0; r < 4; ++r){
    int row = wave*32 + m*16 + kch*4 + r;
    float inv = 1.0f / nrm[row];
    #pragma unroll
    for (int n = 0; n < 4; ++n){
      float v = acc[m][n][r] * inv;
      att[((size_t)b*Nn + n0 + row)*D + h*64 + n*16 + fr] = f2bf(v);
    }
  }
}

extern "C" void kernel_launch(void* const* d_in, const int* in_sizes, int n_in,
                              void* d_out, int out_size, void* d_ws, size_t ws_size,
                              hipStream_t stream)
{
  (void)in_sizes; (void)n_in; (void)out_size; (void)ws_size;
  const float* query = (const float*)d_in[0];
  const float* Wq = (const float*)d_in[1];
  const float* bq = (const float*)d_in[2];
  const float* Wk = (const float*)d_in[3];
  const float* bk = (const float*)d_in[4];
  const float* Wv = (const float*)d_in[5];
  const float* bv = (const float*)d_in[6];
  const float* Wo = (const float*)d_in[7];
  const float* bo = (const float*)d_in[8];
  const float* proj = (const float*)d_in[9];

  const int B = 4, N = 4096, D = 1024, H = 16;
  const size_t NT = (size_t)B*N*D;       // 16,777,216

  char* ws = (char*)d_ws;
  unsigned short* qbf = (unsigned short*)ws;               // NT bf16 (reused as att)
  unsigned short* wqb = (unsigned short*)(ws + 33554432);  // stacked W: wq|wk|wv|wo
  unsigned short* wkb = wqb + 1048576;
  unsigned short* wvb = wkb + 1048576;
  unsigned short* wob = wvb + 1048576;
  unsigned short* pjb = wob + 1048576;                     // 65536 bf16
  unsigned short* qb  = pjb + 65536;                       // NT bf16
  unsigned short* kb  = qb + NT;                           // NT bf16 (reused as Vtp)
  unsigned short* vb  = kb + NT;                           // NT bf16
  float* kdiag = (float*)(vb + NT);                        // B*H*N f32
  float* stab  = kdiag + 262144;                           // 64 f32
  float* ksum  = stab + 64;                                // 4096 f32
  unsigned short* ktp = (unsigned short*)(ksum + 4096);    // [BH][64][N] bf16
  float* kvp = (float*)(ktp + NT);                         // 8*64*64*64 f32
  // d_out (67MB f32) doubles as scratch:
  float* dd = (float*)d_out;                               // [BH][N][64] f32
  unsigned short* qprime = (unsigned short*)d_out;         // [BH][N][64] bf16
  unsigned short* att = qbf;                               // [B*N][D] bf16
  unsigned short* vtp = kb;                                // [BH][64][N] bf16
  unsigned short* kvt = (unsigned short*)(kvp + 2097152);  // [BH][64][64] bf16

  k_init<<<1, 256, 0, stream>>>(stab, ksum);
  k_cast<<<2048, 256, 0, stream>>>(query, qbf, (int)(NT/4));
  k_cast<<<1024, 256, 0, stream>>>(Wq, wqb, 262144);
  k_cast<<<1024, 256, 0, stream>>>(Wk, wkb, 262144);
  k_cast<<<1024, 256, 0, stream>>>(Wv, wvb, 262144);
  k_cast<<<1024, 256, 0, stream>>>(Wo, wob, 262144);
  k_cast<<<64, 256, 0, stream>>>(proj, pjb, 16384);

  // fused QKV GEMM: W stacked rows [3072][1024]
  gemm256<0><<<dim3(64, 12), 512, 0, stream>>>(qbf, wqb, bq, bk, bv,
                                               qb, kb, vb, nullptr, B*N, 3072, D);

  dim3 gf(32, 64);
  k_favor_k1<<<gf, 256, 0, stream>>>(kb, pjb, dd, kdiag, stab, N, D, H);
  k_favor_k2<<<gf, 256, 0, stream>>>(dd, kdiag, stab, ktp, ksum, N);
  k_favor_q <<<gf, 256, 0, stream>>>(qb, pjb, qprime, N, D, H);
  k_vtrans  <<<gf, 256, 0, stream>>>(vb, vtp, N, D, H);

  k_kv<<<dim3(8, 64), 256, 0, stream>>>(ktp, vtp, kvp, N);
  k_kvred<<<64, 256, 0, stream>>>(kvp, kvt);
  k_qkv<<<gf, 256, 0, stream>>>(qprime, kvt, ksum, att, N, D, H);

  gemm256<1><<<dim3(64, 4), 512, 0, stream>>>(att, wob, bo, nullptr, nullptr,
                                              nullptr, nullptr, nullptr,
                                              (float*)d_out, B*N, D, D);
}

// Round 3
// 260.506 us; speedup vs baseline: 1.3779x; 1.1832x over previous
//
#include <hip/hip_runtime.h>
#include <hip/hip_bf16.h>

using floatx4 = __attribute__((ext_vector_type(4))) float;
using bf16x8  = __attribute__((ext_vector_type(8))) __bf16;
using uintx4  = __attribute__((ext_vector_type(4))) unsigned int;

#define DEV __device__ __forceinline__

DEV unsigned short f2bf(float f){
  unsigned u = __float_as_uint(f);
  u = (u + 0x7FFFu + ((u >> 16) & 1u)) >> 16;   // RNE
  return (unsigned short)u;
}
DEV float bf2f(unsigned short h){ return __uint_as_float(((unsigned)h) << 16); }

DEV void gload_lds16(const void* g, void* l){
  __builtin_amdgcn_global_load_lds((const __attribute__((address_space(1))) void*)g,
                                   (__attribute__((address_space(3))) void*)l, 16, 0, 0);
}

DEV void atomicMaxF(float* a, float v){
  if (v >= 0.f) atomicMax((int*)a, __float_as_int(v));
  else          atomicMin((unsigned int*)a, __float_as_uint(v));
}

#define SBAR do{ __builtin_amdgcn_sched_barrier(0); __builtin_amdgcn_s_barrier(); \
                 __builtin_amdgcn_sched_barrier(0); }while(0)

// ---------------------------------------------------------------------------
// prep: all f32->bf16 casts + zero-init, one launch.
// blocks [0,1024): query; [1024,1280): W's; [1280,1296): proj; 1296: zeros.
__global__ __launch_bounds__(256) void k_prep(
    const float* __restrict__ query, const float* __restrict__ Wq,
    const float* __restrict__ Wk, const float* __restrict__ Wv,
    const float* __restrict__ Wo, const float* __restrict__ proj,
    unsigned short* __restrict__ qbf, unsigned short* __restrict__ wqb,
    unsigned short* __restrict__ wkb, unsigned short* __restrict__ wvb,
    unsigned short* __restrict__ wob, unsigned short* __restrict__ pjb,
    float* __restrict__ esum, float* __restrict__ vsum, float* __restrict__ stab)
{
  const int bid = blockIdx.x, tid = threadIdx.x;
  const float* s; unsigned short* d; int i, stride, n4;
  if (bid < 1024){ s = query; d = qbf; i = bid*256 + tid; stride = 262144; n4 = 4194304; }
  else if (bid < 1280){
    int w = (bid - 1024) >> 6;
    s = (w==0)?Wq:(w==1)?Wk:(w==2)?Wv:Wo;
    d = (w==0)?wqb:(w==1)?wkb:(w==2)?wvb:wob;
    i = ((bid-1024)&63)*256 + tid; stride = 16384; n4 = 262144;
  } else if (bid < 1296){ s = proj; d = pjb; i = (bid-1280)*256 + tid; stride = 4096; n4 = 16384; }
  else {
    for (int k = tid; k < 4096; k += 256){ esum[k] = 0.f; vsum[k] = 0.f; }
    if (tid < 64) stab[tid] = -1e30f;
    return;
  }
  for (; i < n4; i += stride){
    float4 v = ((const float4*)s)[i];
    ushort4 o;
    o.x = f2bf(v.x); o.y = f2bf(v.y); o.z = f2bf(v.z); o.w = f2bf(v.w);
    ((ushort4*)d)[i] = o;
  }
}

// ---------------------------------------------------------------------------
// 256x256 GEMM, BK=64, 2 LDS buffers, 4 phases/K-tile, unit-granular counted
// vmcnt(4), XOR slot swizzle (both sides). C[m,n] = sum_k A[m,k]*W[n,k]+bias.
// LDS buffer: 64KB = A[2 khalf][256 rows][64B] + B same. 8 waves (2Mx4N).
template<int OUTMODE>
__global__ __launch_bounds__(512, 1) void gemm256(
    const unsigned short* __restrict__ A,
    const unsigned short* __restrict__ W,
    const float* __restrict__ bias0, const float* __restrict__ bias1,
    const float* __restrict__ bias2,
    unsigned short* __restrict__ out0, unsigned short* __restrict__ out1,
    unsigned short* __restrict__ out2,
    float* __restrict__ outf, int M, int Nout, int K)
{
  __shared__ __align__(16) char lds[131072];
  const int tid  = threadIdx.x;
  const int wid  = tid >> 6, lane = tid & 63;
  const int wr   = wid >> 2, wc = wid & 3;
  const int fr   = lane & 15, kch = lane >> 4;
  const int m0   = blockIdx.x * 256, n0 = blockIdx.y * 256;
  const int NU   = (K >> 6) * 4;                  // total stage units
  const size_t Kb = (size_t)K * 2;

  // staging lane constants: 4 lanes/row (64B khalf), swizzled source slot
  const int ssw = (((lane & 3) ^ ((lane >> 3) & 3))) * 16;
  const char* Arow = (const char*)A + (size_t)(m0 + wid*16 + (lane >> 2))*Kb + ssw;
  const char* Brow = (const char*)W + (size_t)(n0 + wid*16 + (lane >> 2))*Kb + ssw;

  auto stage = [&](int u){
    if (u >= NU) return;
    int T = u >> 2, q = u & 3, isB = q & 1, s = q >> 1;
    char* dst = lds + (T & 1)*65536 + isB*32768 + s*16384 + wid*1024;
    const char* src = (isB ? Brow : Arow) + (size_t)T*128 + s*64;
    gload_lds16(src, dst);
    gload_lds16(src + 128*Kb, dst + 8192);
  };

  // prologue: tile 0's 4 units (8 loads/wave)
  stage(0); stage(1); stage(2); stage(3);

  const int rkey = (fr >> 1) & 3;
  const int aBase = (wr*128 + fr)*64 + (kch ^ rkey)*16;
  const int bBase = 32768 + (wc*64 + fr)*64 + (kch ^ rkey)*16;
  floatx4 acc[8][4] = {};
  bf16x8 a[4], bq[4];

  const int NTt = K >> 6;
  for (int T = 0; T < NTt; ++T){
    const char* buf = lds + (T & 1)*65536;
    // ---- phase 0: s=0, mt 0-3 (+ B s0)
    asm volatile("s_waitcnt vmcnt(4)" ::: "memory");
    SBAR;
    #pragma unroll
    for (int mt = 0; mt < 4; ++mt) a[mt]  = *(const bf16x8*)(buf + aBase + mt*1024);
    #pragma unroll
    for (int nt = 0; nt < 4; ++nt) bq[nt] = *(const bf16x8*)(buf + bBase + nt*1024);
    stage(T*4 + 4);
    __builtin_amdgcn_s_setprio(1);
    #pragma unroll
    for (int mt = 0; mt < 4; ++mt)
      #pragma unroll
      for (int nt = 0; nt < 4; ++nt)
        acc[mt][nt] = __builtin_amdgcn_mfma_f32_16x16x32_bf16(a[mt], bq[nt], acc[mt][nt], 0, 0, 0);
    __builtin_amdgcn_s_setprio(0);
    // ---- phase 1: s=0, mt 4-7
    #pragma unroll
    for (int mt = 0; mt < 4; ++mt) a[mt] = *(const bf16x8*)(buf + aBase + (4+mt)*1024);
    stage(T*4 + 5);
    __builtin_amdgcn_s_setprio(1);
    #pragma unroll
    for (int mt = 0; mt < 4; ++mt)
      #pragma unroll
      for (int nt = 0; nt < 4; ++nt)
        acc[4+mt][nt] = __builtin_amdgcn_mfma_f32_16x16x32_bf16(a[mt], bq[nt], acc[4+mt][nt], 0, 0, 0);
    __builtin_amdgcn_s_setprio(0);
    // ---- phase 2: s=1, mt 0-3 (+ B s1)
    asm volatile("s_waitcnt vmcnt(4)" ::: "memory");
    SBAR;
    #pragma unroll
    for (int mt = 0; mt < 4; ++mt) a[mt]  = *(const bf16x8*)(buf + 16384 + aBase + mt*1024);
    #pragma unroll
    for (int nt = 0; nt < 4; ++nt) bq[nt] = *(const bf16x8*)(buf + 16384 + bBase + nt*1024);
    stage(T*4 + 6);
    __builtin_amdgcn_s_setprio(1);
    #pragma unroll
    for (int mt = 0; mt < 4; ++mt)
      #pragma unroll
      for (int nt = 0; nt < 4; ++nt)
        acc[mt][nt] = __builtin_amdgcn_mfma_f32_16x16x32_bf16(a[mt], bq[nt], acc[mt][nt], 0, 0, 0);
    __builtin_amdgcn_s_setprio(0);
    // ---- phase 3: s=1, mt 4-7
    #pragma unroll
    for (int mt = 0; mt < 4; ++mt) a[mt] = *(const bf16x8*)(buf + 16384 + aBase + (4+mt)*1024);
    stage(T*4 + 7);
    __builtin_amdgcn_s_setprio(1);
    #pragma unroll
    for (int mt = 0; mt < 4; ++mt)
      #pragma unroll
      for (int nt = 0; nt < 4; ++nt)
        acc[4+mt][nt] = __builtin_amdgcn_mfma_f32_16x16x32_bf16(a[mt], bq[nt], acc[4+mt][nt], 0, 0, 0);
    __builtin_amdgcn_s_setprio(0);
  }

  if (OUTMODE == 0){
    const int which = n0 >> 10;
    const float* bb = (which == 0) ? bias0 : (which == 1) ? bias1 : bias2;
    unsigned short* oo = (which == 0) ? out0 : (which == 1) ? out1 : out2;
    #pragma unroll
    for (int nf = 0; nf < 4; ++nf){
      int col = n0 + wc*64 + nf*16 + fr;
      int cl  = col & 1023;
      float bv = bb[cl];
      #pragma unroll
      for (int mf = 0; mf < 8; ++mf)
        #pragma unroll
        for (int r = 0; r < 4; ++r){
          int row = m0 + wr*128 + mf*16 + kch*4 + r;
          oo[(size_t)row*1024 + cl] = f2bf(acc[mf][nf][r] + bv);
        }
    }
  } else {
    #pragma unroll
    for (int nf = 0; nf < 4; ++nf){
      int col = n0 + wc*64 + nf*16 + fr;
      float bv = bias0[col];
      #pragma unroll
      for (int mf = 0; mf < 8; ++mf)
        #pragma unroll
        for (int r = 0; r < 4; ++r){
          int row = m0 + wr*128 + mf*16 + kch*4 + r;
          outf[(size_t)row*Nout + col] = acc[mf][nf][r] + bv;
        }
    }
  }
}

// ---- FAVOR+ -----------------------------------------------------------------
#define CS 0.35355339059327373f   /* 64^-0.25 */

// fused K-side FAVOR: dd -> e = ratio*exp(dd-diag) (stab deferred), transpose
// to Ktp[bh][j][n] bf16, esum partial, global stab via atomicMax.
__global__ __launch_bounds__(256) void k_favor_k(const unsigned short* __restrict__ Kb,
                                                 const unsigned short* __restrict__ Pb,
                                                 unsigned short* __restrict__ Ktp,
                                                 float* __restrict__ esum,
                                                 float* __restrict__ stab,
                                                 int Nn, int D, int H)
{
  __shared__ __align__(16) unsigned short Qs[128*64];
  __shared__ __align__(16) unsigned short Ps[64*64];
  __shared__ __align__(16) unsigned short T[64*136];
  __shared__ float diag_s[128];
  __shared__ float wm[4];
  const int tid = threadIdx.x, wave = tid >> 6, lane = tid & 63;
  const int bh = blockIdx.y, h = bh % H, b = bh / H;
  const int n0 = blockIdx.x * 128;
  const int fr = lane & 15, kch = lane >> 4;
  const int sr = lane >> 3, sc = (lane & 7) * 8;
  #pragma unroll
  for (int q = 0; q < 4; ++q){
    int seg = wave*4 + q;
    gload_lds16(Kb + ((size_t)b*Nn + n0 + seg*8 + sr)*D + h*64 + sc, (char*)Qs + seg*1024);
  }
  #pragma unroll
  for (int q = 0; q < 2; ++q){
    int seg = wave*2 + q;
    gload_lds16(Pb + (size_t)h*4096 + seg*512 + lane*8, (char*)Ps + seg*1024);
  }
  __syncthreads();
  {
    int row = tid >> 1, half = tid & 1;
    float s = 0.f;
    for (int i = 0; i < 32; ++i){
      int d = half*32 + ((row + i) & 31);
      float x = bf2f(Qs[row*64 + d]);
      s += x*x;
    }
    float o = __shfl_xor(s, 1);
    if (half == 0) diag_s[row] = 0.0625f * (s + o);
  }
  floatx4 acc[2][4] = {};
  #pragma unroll
  for (int ks = 0; ks < 2; ++ks){
    bf16x8 af[2], bfr[4];
    #pragma unroll
    for (int m = 0; m < 2; ++m)
      af[m] = *(const bf16x8*)((const char*)Qs + (wave*32 + m*16 + fr)*128 + ks*64 + kch*16);
    #pragma unroll
    for (int n = 0; n < 4; ++n)
      bfr[n] = *(const bf16x8*)((const char*)Ps + (n*16 + fr)*128 + ks*64 + kch*16);
    #pragma unroll
    for (int m = 0; m < 2; ++m)
      #pragma unroll
      for (int n = 0; n < 4; ++n)
        acc[m][n] = __builtin_amdgcn_mfma_f32_16x16x32_bf16(af[m], bfr[n], acc[m][n], 0, 0, 0);
  }
  __syncthreads();   // diag_s ready
  float mx = -1e30f;
  #pragma unroll
  for (int m = 0; m < 2; ++m)
  #pragma unroll
  for (int r = 0; r < 4; ++r){
    int row = wave*32 + m*16 + kch*4 + r;
    float dg = diag_s[row];
    #pragma unroll
    for (int n = 0; n < 4; ++n){
      float dd = CS * acc[m][n][r];
      mx = fmaxf(mx, dd);
      float e = 0.125f * __expf(dd - dg);
      T[(n*16 + fr)*136 + row] = f2bf(e);
    }
  }
  #pragma unroll
  for (int off = 1; off < 64; off <<= 1) mx = fmaxf(mx, __shfl_xor(mx, off));
  if (lane == 0) wm[wave] = mx;
  __syncthreads();   // T complete + wm ready
  if (tid == 0) atomicMaxF(&stab[bh], fmaxf(fmaxf(wm[0],wm[1]), fmaxf(wm[2],wm[3])));
  {
    int j = tid >> 2, part = tid & 3;
    float s = 0.f;
    for (int i = 0; i < 32; ++i) s += bf2f(T[j*136 + part*32 + i]);
    s += __shfl_xor(s, 1); s += __shfl_xor(s, 2);
    if (part == 0) atomicAdd(&esum[bh*64 + j], s);
  }
  for (int it = 0; it < 4; ++it){
    int sidx = it*256 + tid;
    int j = sidx >> 4, nn = (sidx & 15) * 8;
    uintx4 v = *(const uintx4*)((const char*)T + (j*136 + nn)*2);
    *(uintx4*)(Ktp + ((size_t)bh*64 + j)*Nn + n0 + nn) = v;
  }
}

__global__ __launch_bounds__(256) void k_vtrans(const unsigned short* __restrict__ Vb,
                                                unsigned short* __restrict__ Vtp,
                                                float* __restrict__ vsum,
                                                int Nn, int D, int H)
{
  __shared__ __align__(16) unsigned short T[64*136];
  const int tid = threadIdx.x;
  const int bh = blockIdx.y, h = bh % H, b = bh / H;
  const int n0 = blockIdx.x * 128;
  for (int it = 0; it < 4; ++it){
    int s8 = it*256 + tid;
    int n = s8 >> 3, d0 = (s8 & 7) * 8;
    uintx4 v = *(const uintx4*)(Vb + ((size_t)b*Nn + n0 + n)*D + h*64 + d0);
    const unsigned short* us = (const unsigned short*)&v;
    #pragma unroll
    for (int ii = 0; ii < 8; ++ii) T[(d0+ii)*136 + n] = us[ii];
  }
  __syncthreads();
  {
    int d = tid >> 2, part = tid & 3;
    float s = 0.f;
    for (int i = 0; i < 32; ++i) s += bf2f(T[d*136 + part*32 + i]);
    s += __shfl_xor(s, 1); s += __shfl_xor(s, 2);
    if (part == 0) atomicAdd(&vsum[bh*64 + d], s);
  }
  for (int it = 0; it < 4; ++it){
    int sidx = it*256 + tid;
    int d = sidx >> 4, nn = (sidx & 15) * 8;
    uintx4 v = *(const uintx4*)((const char*)T + (d*136 + nn)*2);
    *(uintx4*)(Vtp + ((size_t)bh*64 + d)*Nn + n0 + nn) = v;
  }
}

__global__ __launch_bounds__(256) void k_kv(const unsigned short* __restrict__ Ktp,
                                            const unsigned short* __restrict__ Vtp,
                                            float* __restrict__ kvp, int Nn)
{
  __shared__ __align__(16) unsigned short As[64*32];
  __shared__ __align__(16) unsigned short Bs[64*32];
  const int tid = threadIdx.x, wave = tid >> 6, lane = tid & 63;
  const int ks = blockIdx.x, bh = blockIdx.y;
  const int base = ks * 512;
  const int fr = lane & 15, kch = lane >> 4;
  const int sr = lane >> 2, sc = (lane & 3) * 8;
  floatx4 acc[4] = {};
  for (int kk = 0; kk < 512; kk += 32){
    gload_lds16(Ktp + ((size_t)bh*64 + wave*16 + sr)*Nn + base + kk + sc, (char*)As + wave*1024);
    gload_lds16(Vtp + ((size_t)bh*64 + wave*16 + sr)*Nn + base + kk + sc, (char*)Bs + wave*1024);
    __syncthreads();
    bf16x8 af = *(const bf16x8*)((const char*)As + (wave*16 + fr)*64 + kch*16);
    #pragma unroll
    for (int n = 0; n < 4; ++n){
      bf16x8 bfr = *(const bf16x8*)((const char*)Bs + (n*16 + fr)*64 + kch*16);
      acc[n] = __builtin_amdgcn_mfma_f32_16x16x32_bf16(af, bfr, acc[n], 0, 0, 0);
    }
    __syncthreads();
  }
  #pragma unroll
  for (int n = 0; n < 4; ++n)
  #pragma unroll
  for (int r = 0; r < 4; ++r){
    int j = wave*16 + kch*4 + r;
    int d = n*16 + fr;
    kvp[((size_t)(ks*64 + bh)*64 + j)*64 + d] = acc[n][r];
  }
}

// reduce over KS, apply deferred stab + eps terms:
// kvt[bh][d][j] = s*kv_e[j][d] + 1e-4*vsum[d];  ksumf[bh][j] = s*esum[j] + 1e-4*N
__global__ __launch_bounds__(256) void k_kvred(const float* __restrict__ kvp,
                                               const float* __restrict__ stab,
                                               const float* __restrict__ esum,
                                               const float* __restrict__ vsum,
                                               unsigned short* __restrict__ Kvt,
                                               float* __restrict__ ksumf){
  const int bh = blockIdx.x, tid = threadIdx.x;
  const float s = __expf(-stab[bh]);
  for (int i = 0; i < 16; ++i){
    int idx = i*256 + tid;
    int j = idx >> 6, d = idx & 63;
    float sum = 0.f;
    #pragma unroll
    for (int ks = 0; ks < 8; ++ks) sum += kvp[((size_t)(ks*64 + bh)*64 + j)*64 + d];
    Kvt[((size_t)bh*64 + d)*64 + j] = f2bf(s*sum + 1e-4f*vsum[bh*64 + d]);
  }
  if (tid < 64) ksumf[bh*64 + tid] = s*esum[bh*64 + tid] + 0.4096f;
}

// fused Q-side FAVOR + PV + normalize -> att
__global__ __launch_bounds__(256) void k_qattn(const unsigned short* __restrict__ Qb,
                                               const unsigned short* __restrict__ Pb,
                                               const unsigned short* __restrict__ Kvt,
                                               const float* __restrict__ ksumf,
                                               unsigned short* __restrict__ att,
                                               int Nn, int D, int H)
{
  __shared__ __align__(16) unsigned short Qs[128*64];
  __shared__ __align__(16) unsigned short Ps[64*64];
  __shared__ __align__(16) unsigned short Ks[64*64];
  __shared__ __align__(16) unsigned short Q2[128*64];
  __shared__ float ksum_s[64];
  __shared__ float diag_s[128];
  __shared__ float nrm[128];
  const int tid = threadIdx.x, wave = tid >> 6, lane = tid & 63;
  const int bh = blockIdx.y, h = bh % H, b = bh / H;
  const int n0 = blockIdx.x * 128;
  const int fr = lane & 15, kch = lane >> 4;
  const int sr = lane >> 3, sc = (lane & 7) * 8;
  #pragma unroll
  for (int q = 0; q < 4; ++q){
    int seg = wave*4 + q;
    gload_lds16(Qb + ((size_t)b*Nn + n0 + seg*8 + sr)*D + h*64 + sc, (char*)Qs + seg*1024);
  }
  #pragma unroll
  for (int q = 0; q < 2; ++q){
    int seg = wave*2 + q;
    gload_lds16(Pb + (size_t)h*4096 + seg*512 + lane*8, (char*)Ps + seg*1024);
    gload_lds16(Kvt + (size_t)bh*4096 + seg*512 + lane*8, (char*)Ks + seg*1024);
  }
  if (tid < 64) ksum_s[tid] = ksumf[bh*64 + tid];
  __syncthreads();
  {
    int row = tid >> 1, half = tid & 1;
    float s = 0.f;
    for (int i = 0; i < 32; ++i){
      int d = half*32 + ((row + i) & 31);
      float x = bf2f(Qs[row*64 + d]);
      s += x*x;
    }
    float o = __shfl_xor(s, 1);
    if (half == 0) diag_s[row] = 0.0625f * (s + o);
  }
  floatx4 acc[2][4] = {};
  #pragma unroll
  for (int ks = 0; ks < 2; ++ks){
    bf16x8 af[2], bfr[4];
    #pragma unroll
    for (int m = 0; m < 2; ++m)
      af[m] = *(const bf16x8*)((const char*)Qs + (wave*32 + m*16 + fr)*128 + ks*64 + kch*16);
    #pragma unroll
    for (int n = 0; n < 4; ++n)
      bfr[n] = *(const bf16x8*)((const char*)Ps + (n*16 + fr)*128 + ks*64 + kch*16);
    #pragma unroll
    for (int m = 0; m < 2; ++m)
      #pragma unroll
      for (int n = 0; n < 4; ++n)
        acc[m][n] = __builtin_amdgcn_mfma_f32_16x16x32_bf16(af[m], bfr[n], acc[m][n], 0, 0, 0);
  }
  __syncthreads();   // diag_s ready
  #pragma unroll
  for (int m = 0; m < 2; ++m)
  #pragma unroll
  for (int r = 0; r < 4; ++r){
    float mxv = -1e30f;
    #pragma unroll
    for (int n = 0; n < 4; ++n) mxv = fmaxf(mxv, acc[m][n][r]);
    mxv = fmaxf(mxv, __shfl_xor(mxv, 1));
    mxv = fmaxf(mxv, __shfl_xor(mxv, 2));
    mxv = fmaxf(mxv, __shfl_xor(mxv, 4));
    mxv = fmaxf(mxv, __shfl_xor(mxv, 8));
    int row = wave*32 + m*16 + kch*4 + r;
    float dg = diag_s[row];
    float stabv = CS * mxv;
    float qp[4], pr = 0.f;
    #pragma unroll
    for (int n = 0; n < 4; ++n){
      qp[n] = 0.125f * __expf(CS*acc[m][n][r] - dg - stabv) + 1e-4f;
      pr += qp[n] * ksum_s[n*16 + fr];
    }
    pr += __shfl_xor(pr, 1); pr += __shfl_xor(pr, 2);
    pr += __shfl_xor(pr, 4); pr += __shfl_xor(pr, 8);
    if (fr == 0) nrm[row] = fmaxf(pr, 0.01f);
    #pragma unroll
    for (int n = 0; n < 4; ++n){
      int j = n*16 + fr;
      int slot = (j >> 3) ^ (row & 7);
      ((unsigned short*)Q2)[row*64 + slot*8 + (j & 7)] = f2bf(qp[n]);
    }
  }
  __syncthreads();   // Q2 + nrm ready
  floatx4 acc2[2][4] = {};
  #pragma unroll
  for (int ks = 0; ks < 2; ++ks){
    bf16x8 af[2], bfr[4];
    #pragma unroll
    for (int m = 0; m < 2; ++m){
      int row = wave*32 + m*16 + fr;
      int slot = (ks*4 + kch) ^ (row & 7);
      af[m] = *(const bf16x8*)((const char*)Q2 + row*128 + slot*16);
    }
    #pragma unroll
    for (int n = 0; n < 4; ++n)
      bfr[n] = *(const bf16x8*)((const char*)Ks + (n*16 + fr)*128 + ks*64 + kch*16);
    #pragma unroll
    for (int m = 0; m < 2; ++m)
      #pragma unroll
      for (int n = 0; n < 4; ++n)
        acc2[m][n] = __builtin_amdgcn_mfma_f32_16x16x32_bf16(af[m], bfr[n], acc2[m][n], 0, 0, 0);
  }
  #pragma unroll
  for (int m = 0; m < 2; ++m)
  #pragma unroll
  for (int r = 0; r < 4; ++r){
    int row = wave*32 + m*16 + kch*4 + r;
    float inv = 1.0f / nrm[row];
    #pragma unroll
    for (int n = 0; n < 4; ++n){
      float v = acc2[m][n][r] * inv;
      att[((size_t)b*Nn + n0 + row)*D + h*64 + n*16 + fr] = f2bf(v);
    }
  }
}

extern "C" void kernel_launch(void* const* d_in, const int* in_sizes, int n_in,
                              void* d_out, int out_size, void* d_ws, size_t ws_size,
                              hipStream_t stream)
{
  (void)in_sizes; (void)n_in; (void)out_size; (void)ws_size;
  const float* query = (const float*)d_in[0];
  const float* Wq = (const float*)d_in[1];
  const float* bq = (const float*)d_in[2];
  const float* Wk = (const float*)d_in[3];
  const float* bk = (const float*)d_in[4];
  const float* Wv = (const float*)d_in[5];
  const float* bv = (const float*)d_in[6];
  const float* Wo = (const float*)d_in[7];
  const float* bo = (const float*)d_in[8];
  const float* proj = (const float*)d_in[9];

  const int B = 4, N = 4096, D = 1024, H = 16;
  const size_t NT = (size_t)B*N*D;

  char* ws = (char*)d_ws;
  unsigned short* qbf = (unsigned short*)ws;               // NT bf16 (later: att)
  unsigned short* wqb = (unsigned short*)(ws + 33554432);
  unsigned short* wkb = wqb + 1048576;
  unsigned short* wvb = wkb + 1048576;
  unsigned short* wob = wvb + 1048576;
  unsigned short* pjb = wob + 1048576;                     // 65536
  unsigned short* qb  = pjb + 65536;                       // NT
  unsigned short* kb  = qb + NT;                           // NT (later: vtp)
  unsigned short* vb  = kb + NT;                           // NT
  unsigned short* ktp = vb + NT;                           // NT
  float* kvp  = (float*)(ktp + NT);                        // 8*64*64*64
  unsigned short* kvt = (unsigned short*)(kvp + 2097152);  // 64*64*64
  float* esum = (float*)(kvt + 262144);                    // 4096
  float* vsum = esum + 4096;                               // 4096
  float* ksumf = vsum + 4096;                              // 4096
  float* stab = ksumf + 4096;                              // 64
  unsigned short* att = qbf;
  unsigned short* vtp = kb;

  k_prep<<<1297, 256, 0, stream>>>(query, Wq, Wk, Wv, Wo, proj,
                                   qbf, wqb, wkb, wvb, wob, pjb, esum, vsum, stab);

  gemm256<0><<<dim3(64, 12), 512, 0, stream>>>(qbf, wqb, bq, bk, bv,
                                               qb, kb, vb, nullptr, B*N, 3072, D);

  dim3 gf(32, 64);
  k_favor_k<<<gf, 256, 0, stream>>>(kb, pjb, ktp, esum, stab, N, D, H);
  k_vtrans <<<gf, 256, 0, stream>>>(vb, vtp, vsum, N, D, H);
  k_kv<<<dim3(8, 64), 256, 0, stream>>>(ktp, vtp, kvp, N);
  k_kvred<<<64, 256, 0, stream>>>(kvp, stab, esum, vsum, kvt, ksumf);
  k_qattn<<<gf, 256, 0, stream>>>(qb, pjb, kvt, ksumf, att, N, D, H);

  gemm256<1><<<dim3(64, 4), 512, 0, stream>>>(att, wob, bo, nullptr, nullptr,
                                              nullptr, nullptr, nullptr,
                                              (float*)d_out, B*N, 1024, D);
}